// Round 1
// baseline (166.227 us; speedup 1.0000x reference)
//
#include <hip/hip_runtime.h>
#include <hip/hip_bf16.h>
#include <math.h>

#define B_ 4
#define S_ 2048
#define D_ 256
#define H_ 8
#define HD_ 32

typedef __attribute__((ext_vector_type(8))) short short8;
typedef __attribute__((ext_vector_type(4))) float floatx4;
typedef unsigned short ushort_t;
typedef unsigned int uint_t;

// round-to-nearest-even fp32 -> bf16
__device__ __forceinline__ ushort_t f2bf(float f) {
  union { float f; unsigned u; } v; v.f = f;
  unsigned u = v.u;
  unsigned r = (u + 0x7FFFu + ((u >> 16) & 1u)) >> 16;
  return (ushort_t)r;
}

__global__ __launch_bounds__(256)
void cvt_bf16_v4(const float4* __restrict__ src, uint2* __restrict__ dst, int n4) {
  int i = blockIdx.x * blockDim.x + threadIdx.x;
  if (i < n4) {
    float4 f = src[i];
    uint2 o;
    o.x = (uint_t)f2bf(f.x) | ((uint_t)f2bf(f.y) << 16);
    o.y = (uint_t)f2bf(f.z) | ((uint_t)f2bf(f.w) << 16);
    dst[i] = o;
  }
}

// C = X @ W^T + b for Q,K,V ; writes bf16 in (B,H,S,Hd) layout
__global__ __launch_bounds__(256)
void proj_qkv(const ushort_t* __restrict__ xb,
              const ushort_t* __restrict__ wq, const ushort_t* __restrict__ wk, const ushort_t* __restrict__ wv,
              const float* __restrict__ bq, const float* __restrict__ bk, const float* __restrict__ bv,
              ushort_t* __restrict__ qout, ushort_t* __restrict__ kout, ushort_t* __restrict__ vout)
{
  const int z = blockIdx.z;
  const ushort_t* wb = (z == 0) ? wq : (z == 1) ? wk : wv;
  const float* bias  = (z == 0) ? bq : (z == 1) ? bk : bv;
  ushort_t* dst      = (z == 0) ? qout : (z == 1) ? kout : vout;

  const int l  = threadIdx.x & 63;
  const int w  = threadIdx.x >> 6;
  const int row0 = blockIdx.y * 64 + w * 16;
  const int col0 = blockIdx.x * 64;
  const int lr = l & 15;
  const int lg = l >> 4;
  const int lk = lg * 8;

  floatx4 acc[4] = {};
  const ushort_t* arow = xb + (row0 + lr) * D_ + lk;
#pragma unroll
  for (int kk = 0; kk < D_; kk += 32) {
    short8 a = *(const short8*)(arow + kk);
#pragma unroll
    for (int j = 0; j < 4; ++j) {
      short8 b = *(const short8*)(wb + (col0 + j * 16 + lr) * D_ + kk + lk);
      acc[j] = __builtin_amdgcn_mfma_f32_16x16x32_bf16(a, b, acc[j], 0, 0, 0);
    }
  }
#pragma unroll
  for (int j = 0; j < 4; ++j) {
    int c = col0 + j * 16 + lr;
    float bv_ = bias[c];
    int hh = c >> 5, d = c & 31;
#pragma unroll
    for (int r = 0; r < 4; ++r) {
      int i = row0 + lg * 4 + r;          // D layout: row=(lane>>4)*4+reg
      int bb = i >> 11, s = i & 2047;
      dst[(((bb * H_) + hh) * S_ + s) * HD_ + d] = f2bf(acc[j][r] + bv_);
    }
  }
}

// flash attention: one block = one (b,h) x 64 q-rows; 4 waves x 16 rows
__global__ __launch_bounds__(256)
void attn_kernel(const ushort_t* __restrict__ qb, const ushort_t* __restrict__ kb,
                 const ushort_t* __restrict__ vb, const float* __restrict__ head_scale,
                 ushort_t* __restrict__ hb)
{
  __shared__ ushort_t K_lds[64 * 40];    // padded stride 40 elems (80B)
  __shared__ ushort_t Vt_lds[32 * 72];   // V transposed, stride 72 elems (144B)
  __shared__ ushort_t P_lds[4 * 16 * 72];

  const int tid = threadIdx.x;
  const int l = tid & 63;
  const int w = tid >> 6;
  const int bh = blockIdx.y;   // 0..31
  const int qt = blockIdx.x;   // 0..31
  const int lr = l & 15;
  const int lg = l >> 4;
  const int lk = lg * 8;

  const ushort_t* qp = qb + (size_t)bh * S_ * HD_;
  const ushort_t* kp = kb + (size_t)bh * S_ * HD_;
  const ushort_t* vp = vb + (size_t)bh * S_ * HD_;

  const int q0 = qt * 64 + w * 16;
  short8 qfrag = *(const short8*)(qp + (q0 + lr) * HD_ + lk);

  floatx4 acc0 = {}, acc1 = {};
  float m[4]    = {-INFINITY, -INFINITY, -INFINITY, -INFINITY};
  float lsum[4] = {0.f, 0.f, 0.f, 0.f};

  const int skv = tid >> 2;        // staging: kv row 0..63
  const int sc8 = (tid & 3) * 8;   // staging: d offset

  ushort_t* Pw = P_lds + w * 16 * 72;
  const floatx4 zero4 = {0.f, 0.f, 0.f, 0.f};

  for (int t0 = 0; t0 < S_; t0 += 64) {
    // ---- stage K (row-major padded) and V (transposed) ----
    uint4 kv4 = *(const uint4*)(kp + (t0 + skv) * HD_ + sc8);
    uint4 vv4 = *(const uint4*)(vp + (t0 + skv) * HD_ + sc8);
    *(uint4*)&K_lds[skv * 40 + sc8] = kv4;
    const ushort_t* vs = (const ushort_t*)&vv4;
#pragma unroll
    for (int i = 0; i < 8; ++i) Vt_lds[(sc8 + i) * 72 + skv] = vs[i];
    __syncthreads();

    // ---- QK^T: 4 MFMAs (K=32=Hd in one shot) ----
    float p[4][4];
#pragma unroll
    for (int j = 0; j < 4; ++j) {
      short8 bfr = *(const short8*)&K_lds[(j * 16 + lr) * 40 + lk];
      floatx4 s = __builtin_amdgcn_mfma_f32_16x16x32_bf16(qfrag, bfr, zero4, 0, 0, 0);
#pragma unroll
      for (int r = 0; r < 4; ++r) p[j][r] = s[r] * 0.17677669529663687f; // 1/sqrt(32)
    }

    // ---- online softmax (rows = lg*4+r, cols spread over 16-lane group) ----
#pragma unroll
    for (int r = 0; r < 4; ++r) {
      float v = fmaxf(fmaxf(p[0][r], p[1][r]), fmaxf(p[2][r], p[3][r]));
      v = fmaxf(v, __shfl_xor(v, 1, 64));
      v = fmaxf(v, __shfl_xor(v, 2, 64));
      v = fmaxf(v, __shfl_xor(v, 4, 64));
      v = fmaxf(v, __shfl_xor(v, 8, 64));
      float mnew = fmaxf(m[r], v);
      float alpha = __expf(m[r] - mnew);
      m[r] = mnew;
      float ps = 0.f;
#pragma unroll
      for (int j = 0; j < 4; ++j) { p[j][r] = __expf(p[j][r] - mnew); ps += p[j][r]; }
      ps += __shfl_xor(ps, 1, 64);
      ps += __shfl_xor(ps, 2, 64);
      ps += __shfl_xor(ps, 4, 64);
      ps += __shfl_xor(ps, 8, 64);
      lsum[r] = lsum[r] * alpha + ps;
      acc0[r] *= alpha;
      acc1[r] *= alpha;
    }

    // ---- P -> LDS (re-layout to MFMA A-fragment) ----
#pragma unroll
    for (int j = 0; j < 4; ++j)
#pragma unroll
      for (int r = 0; r < 4; ++r)
        Pw[(lg * 4 + r) * 72 + j * 16 + lr] = f2bf(p[j][r]);

    // ---- PV: O[16x32] += P[16x64] @ V[64x32] ----
#pragma unroll
    for (int kk = 0; kk < 2; ++kk) {
      short8 afr = *(const short8*)&Pw[lr * 72 + kk * 32 + lk];
      short8 b0  = *(const short8*)&Vt_lds[lr * 72 + kk * 32 + lk];
      short8 b1  = *(const short8*)&Vt_lds[(16 + lr) * 72 + kk * 32 + lk];
      acc0 = __builtin_amdgcn_mfma_f32_16x16x32_bf16(afr, b0, acc0, 0, 0, 0);
      acc1 = __builtin_amdgcn_mfma_f32_16x16x32_bf16(afr, b1, acc1, 0, 0, 0);
    }
    __syncthreads();
  }

  // ---- epilogue: /lsum, *head_scale, write Hctx (B,S,D) bf16 ----
  const int bb = bh >> 3, hh = bh & 7;
  float hscale = head_scale[hh];
#pragma unroll
  for (int r = 0; r < 4; ++r) {
    float inv = hscale / lsum[r];
    int s = q0 + lg * 4 + r;
    size_t base = ((size_t)(bb * S_ + s)) * D_ + hh * HD_;
    hb[base + lr]      = f2bf(acc0[r] * inv);
    hb[base + 16 + lr] = f2bf(acc1[r] * inv);
  }
}

// out = Hctx @ Wo^T + bo  (fp32 out)
__global__ __launch_bounds__(256)
void proj_out(const ushort_t* __restrict__ hbm, const ushort_t* __restrict__ wo,
              const float* __restrict__ bo, float* __restrict__ out)
{
  const int l = threadIdx.x & 63;
  const int w = threadIdx.x >> 6;
  const int row0 = blockIdx.y * 64 + w * 16;
  const int col0 = blockIdx.x * 64;
  const int lr = l & 15, lg = l >> 4, lk = lg * 8;

  floatx4 acc[4] = {};
  const ushort_t* arow = hbm + (row0 + lr) * D_ + lk;
#pragma unroll
  for (int kk = 0; kk < D_; kk += 32) {
    short8 a = *(const short8*)(arow + kk);
#pragma unroll
    for (int j = 0; j < 4; ++j) {
      short8 b = *(const short8*)(wo + (col0 + j * 16 + lr) * D_ + kk + lk);
      acc[j] = __builtin_amdgcn_mfma_f32_16x16x32_bf16(a, b, acc[j], 0, 0, 0);
    }
  }
#pragma unroll
  for (int j = 0; j < 4; ++j) {
    int c = col0 + j * 16 + lr;
    float bias = bo[c];
#pragma unroll
    for (int r = 0; r < 4; ++r) {
      int i = row0 + lg * 4 + r;
      out[(size_t)i * D_ + c] = acc[j][r] + bias;
    }
  }
}

extern "C" void kernel_launch(void* const* d_in, const int* in_sizes, int n_in,
                              void* d_out, int out_size, void* d_ws, size_t ws_size,
                              hipStream_t stream) {
  (void)in_sizes; (void)n_in; (void)out_size; (void)ws_size;
  const float* x  = (const float*)d_in[0];
  const float* Wq = (const float*)d_in[1];
  const float* bq = (const float*)d_in[2];
  const float* Wk = (const float*)d_in[3];
  const float* bk = (const float*)d_in[4];
  const float* Wv = (const float*)d_in[5];
  const float* bv = (const float*)d_in[6];
  const float* Wo = (const float*)d_in[7];
  const float* bo = (const float*)d_in[8];
  const float* hs = (const float*)d_in[9];

  char* ws = (char*)d_ws;
  ushort_t* xb  = (ushort_t*)ws;                      // 2M elems (4 MiB)
  ushort_t* wqb = (ushort_t*)(ws + 4 * 1024 * 1024);  // 64K each
  ushort_t* wkb = wqb + 65536;
  ushort_t* wvb = wkb + 65536;
  ushort_t* wob = wvb + 65536;
  ushort_t* qb  = wob + 65536;                        // 2M
  ushort_t* kbb = qb + 2097152;                       // 2M
  ushort_t* vbb = kbb + 2097152;                      // 2M
  ushort_t* hbb = xb;                                 // alias: x dead after proj

  cvt_bf16_v4<<<2048, 256, 0, stream>>>((const float4*)x,  (uint2*)xb,  524288);
  cvt_bf16_v4<<<64,   256, 0, stream>>>((const float4*)Wq, (uint2*)wqb, 16384);
  cvt_bf16_v4<<<64,   256, 0, stream>>>((const float4*)Wk, (uint2*)wkb, 16384);
  cvt_bf16_v4<<<64,   256, 0, stream>>>((const float4*)Wv, (uint2*)wvb, 16384);
  cvt_bf16_v4<<<64,   256, 0, stream>>>((const float4*)Wo, (uint2*)wob, 16384);

  proj_qkv<<<dim3(4, 128, 3), 256, 0, stream>>>(xb, wqb, wkb, wvb, bq, bk, bv, qb, kbb, vbb);
  attn_kernel<<<dim3(32, 32), 256, 0, stream>>>(qb, kbb, vbb, hs, hbb);
  proj_out<<<dim3(4, 128), 256, 0, stream>>>(hbb, wob, bo, (float*)d_out);
}

// Round 2
// 110.787 us; speedup vs baseline: 1.5004x; 1.5004x over previous
//
#include <hip/hip_runtime.h>
#include <hip/hip_bf16.h>
#include <math.h>

#define B_ 4
#define S_ 2048
#define D_ 256
#define H_ 8
#define HD_ 32

typedef __attribute__((ext_vector_type(8))) short short8;
typedef __attribute__((ext_vector_type(4))) short short4v;
typedef __attribute__((ext_vector_type(4))) float floatx4;
typedef unsigned short ushort_t;
typedef unsigned int uint_t;

typedef union { unsigned u[2]; short4v v4; } PkU;

// v_cvt_pk_bf16_f32: pack 2 fp32 -> 2 bf16 (RNE), one instruction
#define CVT_PK(DST, LO, HI) \
  asm volatile("v_cvt_pk_bf16_f32 %0, %1, %2" : "=v"(DST) : "v"(LO), "v"(HI))

// D = A(16x16 V^T-slot) * B(16x16 P^T-slot) + D   (bf16 inputs, fp32 acc)
#define MFMA16(ACC, A, B) \
  asm volatile("v_mfma_f32_16x16x16_bf16 %0, %1, %2, %0" : "+v"(ACC) : "v"(A), "v"(B))

// round-to-nearest-even fp32 -> bf16
__device__ __forceinline__ ushort_t f2bf(float f) {
  union { float f; unsigned u; } v; v.f = f;
  unsigned u = v.u;
  unsigned r = (u + 0x7FFFu + ((u >> 16) & 1u)) >> 16;
  return (ushort_t)r;
}

// fused fp32->bf16 conversion for x + all 4 weight matrices (one launch)
__global__ __launch_bounds__(256)
void cvt_all(const float* __restrict__ x,
             const float* __restrict__ wq, const float* __restrict__ wk,
             const float* __restrict__ wv, const float* __restrict__ wo,
             ushort_t* __restrict__ xb,
             ushort_t* __restrict__ wqb, ushort_t* __restrict__ wkb,
             ushort_t* __restrict__ wvb, ushort_t* __restrict__ wob)
{
  const int b = blockIdx.x;
  const float4* s; uint2* d; int i;
  if (b < 2048) {                       // x: 2M elems = 524288 float4
    s = (const float4*)x; d = (uint2*)xb; i = b * 256 + threadIdx.x;
  } else {                              // 4 weights: 16384 float4 each
    int r = b - 2048; int mm = r >> 6;
    s = (const float4*)(mm == 0 ? wq : mm == 1 ? wk : mm == 2 ? wv : wo);
    d = (uint2*)(mm == 0 ? wqb : mm == 1 ? wkb : mm == 2 ? wvb : wob);
    i = (r & 63) * 256 + threadIdx.x;
  }
  float4 f = s[i];
  uint2 o;
  o.x = (uint_t)f2bf(f.x) | ((uint_t)f2bf(f.y) << 16);
  o.y = (uint_t)f2bf(f.z) | ((uint_t)f2bf(f.w) << 16);
  d[i] = o;
}

// C = X @ W^T + b for Q,K,V ; writes bf16 in (B,H,S,Hd) layout
__global__ __launch_bounds__(256)
void proj_qkv(const ushort_t* __restrict__ xb,
              const ushort_t* __restrict__ wq, const ushort_t* __restrict__ wk, const ushort_t* __restrict__ wv,
              const float* __restrict__ bq, const float* __restrict__ bk, const float* __restrict__ bv,
              ushort_t* __restrict__ qout, ushort_t* __restrict__ kout, ushort_t* __restrict__ vout)
{
  const int z = blockIdx.z;
  const ushort_t* wb = (z == 0) ? wq : (z == 1) ? wk : wv;
  const float* bias  = (z == 0) ? bq : (z == 1) ? bk : bv;
  ushort_t* dst      = (z == 0) ? qout : (z == 1) ? kout : vout;

  const int l  = threadIdx.x & 63;
  const int w  = threadIdx.x >> 6;
  const int row0 = blockIdx.y * 64 + w * 16;
  const int col0 = blockIdx.x * 64;
  const int lr = l & 15;
  const int lg = l >> 4;
  const int lk = lg * 8;

  floatx4 acc[4] = {};
  const ushort_t* arow = xb + (row0 + lr) * D_ + lk;
#pragma unroll
  for (int kk = 0; kk < D_; kk += 32) {
    short8 a = *(const short8*)(arow + kk);
#pragma unroll
    for (int j = 0; j < 4; ++j) {
      short8 b = *(const short8*)(wb + (col0 + j * 16 + lr) * D_ + kk + lk);
      acc[j] = __builtin_amdgcn_mfma_f32_16x16x32_bf16(a, b, acc[j], 0, 0, 0);
    }
  }
#pragma unroll
  for (int j = 0; j < 4; ++j) {
    int c = col0 + j * 16 + lr;
    float bv_ = bias[c];
    int hh = c >> 5, d = c & 31;
#pragma unroll
    for (int r = 0; r < 4; ++r) {
      int i = row0 + lg * 4 + r;
      int bb = i >> 11, s = i & 2047;
      dst[(((bb * H_) + hh) * S_ + s) * HD_ + d] = f2bf(acc[j][r] + bv_);
    }
  }
}

// flash attention, swapped-operand layout:
//  S^T = mfma16x16x32(K,Q)  -> lane owns q = lane&15, 16 k-values in regs
//  softmax in-register (4 shuffles/tile), P^T regs ARE the 16x16x16 B-frag
//  O^T = mfma16x16x16(V^T, P^T): col=q stays lane-local for rescale/norm
__global__ __launch_bounds__(256)
void attn_kernel(const ushort_t* __restrict__ qb, const ushort_t* __restrict__ kb,
                 const ushort_t* __restrict__ vb, const float* __restrict__ head_scale,
                 ushort_t* __restrict__ hb)
{
  __shared__ __align__(16) ushort_t K_lds[64 * 40];    // [k][d] stride 40
  __shared__ __align__(16) ushort_t Vt_lds[32 * 72];   // [d][k^swz] stride 72

  const int tid = threadIdx.x;
  const int l = tid & 63;
  const int w = tid >> 6;
  const int bh = blockIdx.y;   // 0..31
  const int qt = blockIdx.x;   // 0..31
  const int lr = l & 15;
  const int lg = l >> 4;

  const ushort_t* qp = qb + (size_t)bh * S_ * HD_;
  const ushort_t* kp = kb + (size_t)bh * S_ * HD_;
  const ushort_t* vp = vb + (size_t)bh * S_ * HD_;

  const int q0 = qt * 64 + w * 16;
  short8 qfrag = *(const short8*)(qp + (q0 + lr) * HD_ + lg * 8);

  floatx4 oA = {}, oB = {};          // O^T: d = lg*4+r (+16 for oB), q = lr
  float m = -INFINITY, lsum = 0.f;

  const int skv = tid >> 2;          // staging: kv row 0..63
  const int sc8 = (tid & 3) * 8;     // staging: d offset
  const int swz_st = (tid & 3) << 4; // Vt store column XOR ((d>>3)&3)<<4
  const int vrow0 = lr * 72, vrow1 = (16 + lr) * 72;
  const int swz0 = ((lr >> 3) & 3) << 4;         // read XOR for d = lr
  const int swz1 = ((2 + (lr >> 3)) & 3) << 4;   // read XOR for d = 16+lr

  const floatx4 zero4 = {0.f, 0.f, 0.f, 0.f};
  const float C2  = 0.25503486f;   // log2(e)/sqrt(32)
  const float THR = 45.25f;        // defer-max threshold (unscaled scores)

  // prefetch tile 0
  uint4 kv4 = *(const uint4*)(kp + skv * HD_ + sc8);
  uint4 vv4 = *(const uint4*)(vp + skv * HD_ + sc8);

  for (int t0 = 0; t0 < S_; t0 += 64) {
    // ---- stage K (row-major) and V (transposed, swizzled) from regs ----
    *(uint4*)&K_lds[skv * 40 + sc8] = kv4;
    {
      const ushort_t* vs = (const ushort_t*)&vv4;
      const int col = skv ^ swz_st;
#pragma unroll
      for (int i = 0; i < 8; ++i) Vt_lds[(sc8 + i) * 72 + col] = vs[i];
    }
    __syncthreads();

    // issue next tile's loads early (latency hides under compute)
    if (t0 + 64 < S_) {
      kv4 = *(const uint4*)(kp + (t0 + 64 + skv) * HD_ + sc8);
      vv4 = *(const uint4*)(vp + (t0 + 64 + skv) * HD_ + sc8);
    }

    // ---- QK^T swapped: sv[s] = S^T[k = s*16+lg*4+r][q = lr] ----
    floatx4 sv[4];
#pragma unroll
    for (int s = 0; s < 4; ++s) {
      short8 kf = *(const short8*)&K_lds[(s * 16 + lr) * 40 + lg * 8];
      sv[s] = __builtin_amdgcn_mfma_f32_16x16x32_bf16(kf, qfrag, zero4, 0, 0, 0);
    }

    // ---- online softmax over k (in-register + 4 shuffles) ----
    float tmax = sv[0][0];
#pragma unroll
    for (int s = 0; s < 4; ++s)
#pragma unroll
      for (int r = 0; r < 4; ++r) tmax = fmaxf(tmax, sv[s][r]);
    tmax = fmaxf(tmax, __shfl_xor(tmax, 16, 64));
    tmax = fmaxf(tmax, __shfl_xor(tmax, 32, 64));

    if (__any(tmax - m > THR)) {           // defer-max: rescale rarely
      float mn = fmaxf(m, tmax);
      float al = exp2f((m - mn) * C2);
      m = mn;
      lsum *= al;
#pragma unroll
      for (int r = 0; r < 4; ++r) { oA[r] *= al; oB[r] *= al; }
    }

    float psum = 0.f;
#pragma unroll
    for (int s = 0; s < 4; ++s)
#pragma unroll
      for (int r = 0; r < 4; ++r) {
        float p = exp2f((sv[s][r] - m) * C2);
        sv[s][r] = p;
        psum += p;
      }
    psum += __shfl_xor(psum, 16, 64);
    psum += __shfl_xor(psum, 32, 64);
    lsum += psum;

    // ---- P^T -> bf16 B-frags (register-only, no LDS round trip) ----
    PkU pk[4];
#pragma unroll
    for (int s = 0; s < 4; ++s) {
      CVT_PK(pk[s].u[0], sv[s][0], sv[s][1]);
      CVT_PK(pk[s].u[1], sv[s][2], sv[s][3]);
    }

    // ---- PV: O^T += V^T-slot * P^T-slot (8x mfma 16x16x16) ----
#pragma unroll
    for (int s = 0; s < 4; ++s) {
      const int col = s * 16 + lg * 4;
      short4v a0 = *(const short4v*)&Vt_lds[vrow0 + (col ^ swz0)];
      short4v a1 = *(const short4v*)&Vt_lds[vrow1 + (col ^ swz1)];
      MFMA16(oA, a0, pk[s].v4);
      MFMA16(oB, a1, pk[s].v4);
    }
    __syncthreads();
  }

  asm volatile("s_nop 7\n\ts_nop 7" :::);   // MFMA->VALU hazard guard
  const int bb = bh >> 3, hh = bh & 7;
  float inv = head_scale[hh] / lsum;
  const int sq = q0 + lr;
  size_t base = ((size_t)(bb * S_ + sq)) * D_ + hh * HD_;
#pragma unroll
  for (int r = 0; r < 4; ++r) {
    int d0 = lg * 4 + r;
    hb[base + d0]      = f2bf(oA[r] * inv);
    hb[base + 16 + d0] = f2bf(oB[r] * inv);
  }
}

// out = Hctx @ Wo^T + bo  (fp32 out)
__global__ __launch_bounds__(256)
void proj_out(const ushort_t* __restrict__ hbm, const ushort_t* __restrict__ wo,
              const float* __restrict__ bo, float* __restrict__ out)
{
  const int l = threadIdx.x & 63;
  const int w = threadIdx.x >> 6;
  const int row0 = blockIdx.y * 64 + w * 16;
  const int col0 = blockIdx.x * 64;
  const int lr = l & 15, lg = l >> 4, lk = lg * 8;

  floatx4 acc[4] = {};
  const ushort_t* arow = hbm + (row0 + lr) * D_ + lk;
#pragma unroll
  for (int kk = 0; kk < D_; kk += 32) {
    short8 a = *(const short8*)(arow + kk);
#pragma unroll
    for (int j = 0; j < 4; ++j) {
      short8 b = *(const short8*)(wo + (col0 + j * 16 + lr) * D_ + kk + lk);
      acc[j] = __builtin_amdgcn_mfma_f32_16x16x32_bf16(a, b, acc[j], 0, 0, 0);
    }
  }
#pragma unroll
  for (int j = 0; j < 4; ++j) {
    int c = col0 + j * 16 + lr;
    float bias = bo[c];
#pragma unroll
    for (int r = 0; r < 4; ++r) {
      int i = row0 + lg * 4 + r;
      out[(size_t)i * D_ + c] = acc[j][r] + bias;
    }
  }
}

extern "C" void kernel_launch(void* const* d_in, const int* in_sizes, int n_in,
                              void* d_out, int out_size, void* d_ws, size_t ws_size,
                              hipStream_t stream) {
  (void)in_sizes; (void)n_in; (void)out_size; (void)ws_size;
  const float* x  = (const float*)d_in[0];
  const float* Wq = (const float*)d_in[1];
  const float* bq = (const float*)d_in[2];
  const float* Wk = (const float*)d_in[3];
  const float* bk = (const float*)d_in[4];
  const float* Wv = (const float*)d_in[5];
  const float* bv = (const float*)d_in[6];
  const float* Wo = (const float*)d_in[7];
  const float* bo = (const float*)d_in[8];
  const float* hs = (const float*)d_in[9];

  char* ws = (char*)d_ws;
  ushort_t* xb  = (ushort_t*)ws;                      // 2M elems (4 MiB)
  ushort_t* wqb = (ushort_t*)(ws + 4 * 1024 * 1024);  // 64K each
  ushort_t* wkb = wqb + 65536;
  ushort_t* wvb = wkb + 65536;
  ushort_t* wob = wvb + 65536;
  ushort_t* qb  = wob + 65536;                        // 2M
  ushort_t* kbb = qb + 2097152;                       // 2M
  ushort_t* vbb = kbb + 2097152;                      // 2M
  ushort_t* hbb = xb;                                 // alias: x dead after proj

  cvt_all<<<2304, 256, 0, stream>>>(x, Wq, Wk, Wv, Wo, xb, wqb, wkb, wvb, wob);
  proj_qkv<<<dim3(4, 128, 3), 256, 0, stream>>>(xb, wqb, wkb, wvb, bq, bk, bv, qb, kbb, vbb);
  attn_kernel<<<dim3(32, 32), 256, 0, stream>>>(qb, kbb, vbb, hs, hbb);
  proj_out<<<dim3(4, 128), 256, 0, stream>>>(hbb, wob, bo, (float*)d_out);
}